// Round 13
// baseline (96.883 us; speedup 1.0000x reference)
//
#include <hip/hip_runtime.h>
#include <math.h>

// Fused Actor network via single-term fp16 MFMA. Round 13: r12 + cross-barrier weight
// pre-issue + depth-2 prefetch everywhere.
// Theory: 59% of issue slots idle (MfmaUtil 15.6 + VALUBusy 25.7). Two latency sources:
// (a) depth-1 prefetch covers only half of ~300cy L2 latency per kc; (b) each of 7
// barriers is followed by a cold dependent weight load. Weight loads touch only ws /
// weight globals (no LDS hazard) -> legally issue BEFORE the preceding barrier.
// Block = 32 samples, 512 threads = 8 waves, LDS 40,960 B -> 2 blocks/CU.
// Weights pre-tiled in d_ws as B-fragment tiles (per-wave 1KB coalesced bursts).
// LDS XOR-swizzle: byte ^= (row&7)<<4.  waves_per_eu(2): allocator gives ~demand,
// no spill (r10/r12 evidence); E1 demand ~102 total regs <= 128 keeps 4 waves/SIMD.

typedef __attribute__((ext_vector_type(8))) _Float16 half8;
typedef __attribute__((ext_vector_type(4))) _Float16 half4;
typedef __attribute__((ext_vector_type(4))) float    f32x4;

#define MFMA16(a, b, c) __builtin_amdgcn_mfma_f32_16x16x32_f16((a), (b), (c), 0, 0, 0)
#define SWZ(row) (((row) & 7) << 4)

#define MT 32
#define T  512

#define S_B      0
#define G1_B     24576
#define G2_B     32768
#define H1_B     24576
#define H2_B     24576
#define LDS_BYTES 40960

#define WS_W1 0
#define WS_W2 49152
#define WS_E1 65536
#define WS_E2 262144
#define WS_EM 327680
#define WS_HALFS 335872
#define WS_BYTES 671744

__device__ __forceinline__ half8 cvt8(const float* __restrict__ p) {
    const float4 a = *reinterpret_cast<const float4*>(p);
    const float4 b = *reinterpret_cast<const float4*>(p + 4);
    half8 r;
    r[0] = (_Float16)a.x; r[1] = (_Float16)a.y; r[2] = (_Float16)a.z; r[3] = (_Float16)a.w;
    r[4] = (_Float16)b.x; r[5] = (_Float16)b.y; r[6] = (_Float16)b.z; r[7] = (_Float16)b.w;
    return r;
}

__global__ __launch_bounds__(256)
void prep_weights(const float* __restrict__ bw1, const float* __restrict__ bw2,
                  const float* __restrict__ ew1, const float* __restrict__ ew2,
                  const float* __restrict__ ewm, _Float16* __restrict__ wsw)
{
    const int i = blockIdx.x * 256 + threadIdx.x;
    if (i >= WS_HALFS) return;
    const float* W; int N, K, KC, j0;
    if      (i < 49152)  { W = bw1; N = 128; K = 376; KC = 12; j0 = i - WS_W1; }
    else if (i < 65536)  { W = bw2; N = 128; K = 128; KC = 4;  j0 = i - WS_W2; }
    else if (i < 262144) { W = ew1; N = 512; K = 376; KC = 12; j0 = i - WS_E1; }
    else if (i < 327680) { W = ew2; N = 256; K = 256; KC = 8;  j0 = i - WS_E2; }
    else                 { W = ewm; N = 34;  K = 128; KC = 4;  j0 = i - WS_EM; }
    const int tile = j0 >> 9;
    const int rem  = j0 & 511;
    const int l    = rem >> 3;
    const int jj   = rem & 7;
    const int n0   = tile / KC, kc = tile - n0 * KC;
    int n = n0 * 16 + (l & 15);
    const int k = kc * 32 + (l >> 4) * 8 + jj;
    float v = 0.f;
    if (W == ewm) {
        const int e = n >> 5, a = n & 31;
        if (a < 17 && k < K) v = ewm[(e * 17 + a) * K + k];
    } else {
        if (n < N && k < K) v = W[n * K + k];
    }
    wsw[i] = (_Float16)v;
}

template <bool USE_WS>
__global__ __launch_bounds__(512)
__attribute__((amdgpu_waves_per_eu(2)))
void actor_kernel(const float* __restrict__ states,
                  const float* __restrict__ bw1, const float* __restrict__ bb1,
                  const float* __restrict__ bw2, const float* __restrict__ bb2,
                  const float* __restrict__ bwo, const float* __restrict__ bbo,
                  const float* __restrict__ ew1, const float* __restrict__ eb1,
                  const float* __restrict__ ew2, const float* __restrict__ eb2,
                  const float* __restrict__ ewm, const float* __restrict__ ebm,
                  const _Float16* __restrict__ wsw,
                  float* __restrict__ out)
{
    extern __shared__ char smc[];
    const int t    = threadIdx.x;
    const int l    = t & 63;
    const int l15  = l & 15;
    const int kgrp = l >> 4;
    const int kg16 = kgrp * 16;
    const int wv   = __builtin_amdgcn_readfirstlane(t >> 6);
    const int base = blockIdx.x * MT;
    const int lB   = l * 8;

    const half8 zf = {0,0,0,0,0,0,0,0};

    const int colA = wv * 16 + l15;
    auto ldW1 = [&](int kc) -> half8 {
        if constexpr (USE_WS) return *(const half8*)(wsw + WS_W1 + (wv * 12 + kc) * 512 + lB);
        else { const int g = kc * 4 + kgrp; return (g < 47) ? cvt8(bw1 + colA * 376 + g * 8) : zf; }
    };
    auto ldW2 = [&](int kc) -> half8 {
        if constexpr (USE_WS) return *(const half8*)(wsw + WS_W2 + (wv * 4 + kc) * 512 + lB);
        else                  return cvt8(bw2 + colA * 128 + (kc * 4 + kgrp) * 8);
    };
    auto ldE1 = [&](int kc, int nt, int ex) -> half8 {
        if constexpr (USE_WS) {
            const int n0 = wv * 2 + nt + ex * 16;
            return *(const half8*)(wsw + WS_E1 + (n0 * 12 + kc) * 512 + lB);
        } else {
            const int g = kc * 4 + kgrp;
            const int wr = wv * 32 + nt * 16 + l15 + ex * 256;
            return (g < 47) ? cvt8(ew1 + wr * 376 + g * 8) : zf;
        }
    };
    auto ldE2 = [&](int kc, int ex) -> half8 {
        if constexpr (USE_WS) {
            return *(const half8*)(wsw + WS_E2 + ((wv + ex * 8) * 8 + kc) * 512 + lB);
        } else {
            const int g = kc * 4 + kgrp;
            return cvt8(ew2 + (colA + ex * 128) * 256 + g * 8);
        }
    };

    // pre-issue A1 kc=0,1 (in flight during HBM staging)
    half8 w0 = ldW1(0), w1 = ldW1(1);

    // ---------- stage ----------
    {
        const float4* src = reinterpret_cast<const float4*>(states + (long)base * 376);
        for (int q = t; q < MT * 94; q += T) {
            const int r  = q / 94;
            const int c4 = q - r * 94;
            const float4 v = src[q];
            half4 h;
            h[0] = (_Float16)v.x; h[1] = (_Float16)v.y;
            h[2] = (_Float16)v.z; h[3] = (_Float16)v.w;
            *(half4*)(smc + S_B + ((r * 768 + c4 * 8) ^ SWZ(r))) = h;
        }
        if (t < MT) {
            *(float4*)(smc + S_B + ((t * 768 + 752) ^ SWZ(t))) = make_float4(0.f, 0.f, 0.f, 0.f);
        }
    }
    __syncthreads();

    // ---------- A1 ----------
    half8 n0a, n0b;
    {
        f32x4 acc[2] = {{0,0,0,0},{0,0,0,0}};
        #pragma unroll
        for (int kc = 0; kc < 12; ++kc) {
            const half8 cur = (kc & 1) ? w1 : w0;
            if (kc + 2 < 12) { if (kc & 1) w1 = ldW1(kc + 2); else w0 = ldW1(kc + 2); }
            const int koff = kc * 64 + kg16;
            #pragma unroll
            for (int mt = 0; mt < 2; ++mt) {
                const int row = mt * 16 + l15;
                const half8 af = *(const half8*)(smc + S_B + ((row * 768 + koff) ^ SWZ(row)));
                acc[mt] = MFMA16(af, cur, acc[mt]);
            }
        }
        n0a = ldW2(0); n0b = ldW2(1);
        const float bias = bb1[colA];
        #pragma unroll
        for (int mt = 0; mt < 2; ++mt) {
            #pragma unroll
            for (int j = 0; j < 4; ++j) {
                const int row = mt * 16 + kgrp * 4 + j;
                const float v = fmaxf(acc[mt][j] + bias, 0.f);
                *(_Float16*)(smc + G1_B + ((row * 256 + colA * 2) ^ SWZ(row))) = (_Float16)v;
            }
        }
    }
    __syncthreads();

    // ---------- A2 ----------
    half8 e1q[2][4];
    {
        f32x4 acc[2] = {{0,0,0,0},{0,0,0,0}};
        w0 = n0a; w1 = n0b;
        #pragma unroll
        for (int kc = 0; kc < 4; ++kc) {
            const half8 cur = (kc & 1) ? w1 : w0;
            if (kc + 2 < 4) { if (kc & 1) w1 = ldW2(kc + 2); else w0 = ldW2(kc + 2); }
            const int koff = kc * 64 + kg16;
            #pragma unroll
            for (int mt = 0; mt < 2; ++mt) {
                const int row = mt * 16 + l15;
                const half8 af = *(const half8*)(smc + G1_B + ((row * 256 + koff) ^ SWZ(row)));
                acc[mt] = MFMA16(af, cur, acc[mt]);
            }
        }
        e1q[0][0] = ldE1(0, 0, 0); e1q[0][1] = ldE1(0, 0, 1);
        e1q[0][2] = ldE1(0, 1, 0); e1q[0][3] = ldE1(0, 1, 1);
        e1q[1][0] = ldE1(1, 0, 0); e1q[1][1] = ldE1(1, 0, 1);
        e1q[1][2] = ldE1(1, 1, 0); e1q[1][3] = ldE1(1, 1, 1);
        const float bias = bb2[colA];
        #pragma unroll
        for (int mt = 0; mt < 2; ++mt) {
            #pragma unroll
            for (int j = 0; j < 4; ++j) {
                const int row = mt * 16 + kgrp * 4 + j;
                const float v = fmaxf(acc[mt][j] + bias, 0.f);
                *(_Float16*)(smc + G2_B + ((row * 256 + colA * 2) ^ SWZ(row))) = (_Float16)v;
            }
        }
    }
    __syncthreads();

    // ---------- A3 ----------
    {
        const int s     = t >> 4;
        const int r     = t & 15;
        const int e     = r & 1;
        const int chunk = r >> 1;
        float z = 0.f;
        const float* wo = bwo + e * 128 + chunk * 16;
        #pragma unroll
        for (int q = 0; q < 2; ++q) {
            const half8 hv = *(const half8*)(smc + G2_B + ((s * 256 + chunk * 32 + q * 16) ^ SWZ(s)));
            const float4 wv0 = *(const float4*)(wo + q * 8);
            const float4 wv1 = *(const float4*)(wo + q * 8 + 4);
            z = fmaf((float)hv[0], wv0.x, z); z = fmaf((float)hv[1], wv0.y, z);
            z = fmaf((float)hv[2], wv0.z, z); z = fmaf((float)hv[3], wv0.w, z);
            z = fmaf((float)hv[4], wv1.x, z); z = fmaf((float)hv[5], wv1.y, z);
            z = fmaf((float)hv[6], wv1.z, z); z = fmaf((float)hv[7], wv1.w, z);
        }
        z += __shfl_xor(z, 2, 64);
        z += __shfl_xor(z, 4, 64);
        z += __shfl_xor(z, 8, 64);
        z += bbo[e];
        const float zo = __shfl_xor(z, 1, 64);
        if (r < 2) {
            const float m = fmaxf(z, zo);
            const float ea = __expf(z - m), eb = __expf(zo - m);
            const float c_self = ea / (ea + eb);
            const _Float16 ch = (_Float16)c_self;
            const _Float16 cl = (_Float16)(c_self - (float)ch);
            union { _Float16 h[2]; unsigned u; } pk;
            pk.h[0] = ch; pk.h[1] = cl;
            *(unsigned*)(smc + S_B + (((s * 768 + 752) ^ SWZ(s)) + e * 4)) = pk.u;
        }
    }
    __syncthreads();

    // ---------- E1 ----------
    half8 e2q[2][2];
    {
        f32x4 aA[2][2], aB[2][2];
        #pragma unroll
        for (int nt = 0; nt < 2; ++nt)
            #pragma unroll
            for (int mt = 0; mt < 2; ++mt) { aA[nt][mt] = {0,0,0,0}; aB[nt][mt] = {0,0,0,0}; }

        #pragma unroll
        for (int kc = 0; kc < 12; ++kc) {
            const int d = kc & 1;
            const half8 c00 = e1q[d][0], c01 = e1q[d][1], c10 = e1q[d][2], c11 = e1q[d][3];
            if (kc + 2 < 12) {
                e1q[d][0] = ldE1(kc + 2, 0, 0); e1q[d][1] = ldE1(kc + 2, 0, 1);
                e1q[d][2] = ldE1(kc + 2, 1, 0); e1q[d][3] = ldE1(kc + 2, 1, 1);
            }
            const int koff = kc * 64 + kg16;
            #pragma unroll
            for (int mt = 0; mt < 2; ++mt) {
                const int row = mt * 16 + l15;
                const half8 af = *(const half8*)(smc + S_B + ((row * 768 + koff) ^ SWZ(row)));
                aA[0][mt] = MFMA16(af, c00, aA[0][mt]);
                aB[0][mt] = MFMA16(af, c01, aB[0][mt]);
                aA[1][mt] = MFMA16(af, c10, aA[1][mt]);
                aB[1][mt] = MFMA16(af, c11, aB[1][mt]);
            }
        }
        e2q[0][0] = ldE2(0, 0); e2q[0][1] = ldE2(0, 1);
        e2q[1][0] = ldE2(1, 0); e2q[1][1] = ldE2(1, 1);
        #pragma unroll
        for (int nt = 0; nt < 2; ++nt) {
            const int col = wv * 32 + nt * 16 + l15;
            const float b0 = eb1[col], b1 = eb1[256 + col];
            #pragma unroll
            for (int mt = 0; mt < 2; ++mt) {
                #pragma unroll
                for (int j = 0; j < 4; ++j) {
                    const int row = mt * 16 + kgrp * 4 + j;
                    const half4 cc = *(const half4*)(smc + S_B + ((row * 768 + 752) ^ SWZ(row)));
                    const float c0 = (float)cc[0] + (float)cc[1];
                    const float c1 = (float)cc[2] + (float)cc[3];
                    float v = c0 * (aA[nt][mt][j] + b0) + c1 * (aB[nt][mt][j] + b1);
                    v = fmaxf(v, 0.f);
                    *(_Float16*)(smc + H1_B + ((row * 512 + col * 2) ^ SWZ(row))) = (_Float16)v;
                }
            }
        }
    }
    __syncthreads();

    // ---------- E2 ----------
    half8 e3a, e3b;
    {
        f32x4 cA[2], cB[2];
        #pragma unroll
        for (int mt = 0; mt < 2; ++mt) { cA[mt] = {0,0,0,0}; cB[mt] = {0,0,0,0}; }
        #pragma unroll
        for (int kc = 0; kc < 8; ++kc) {
            const int d = kc & 1;
            const half8 c0f = e2q[d][0], c1f = e2q[d][1];
            if (kc + 2 < 8) { e2q[d][0] = ldE2(kc + 2, 0); e2q[d][1] = ldE2(kc + 2, 1); }
            const int koff = kc * 64 + kg16;
            #pragma unroll
            for (int mt = 0; mt < 2; ++mt) {
                const int row = mt * 16 + l15;
                const half8 af = *(const half8*)(smc + H1_B + ((row * 512 + koff) ^ SWZ(row)));
                cA[mt] = MFMA16(af, c0f, cA[mt]);
                cB[mt] = MFMA16(af, c1f, cB[mt]);
            }
        }
        {
            const int colt = wv & 1;
            if constexpr (USE_WS) {
                e3a = *(const half8*)(wsw + WS_EM + (colt * 4 + 0) * 512 + lB);
                e3b = *(const half8*)(wsw + WS_EM + ((2 + colt) * 4 + 0) * 512 + lB);
            } else {
                const int col = colt * 16 + l15;
                e3a = (col < 17) ? cvt8(ewm + col * 128 + kgrp * 8)        : zf;
                e3b = (col < 17) ? cvt8(ewm + (17 + col) * 128 + kgrp * 8) : zf;
            }
        }
        __syncthreads();
        const float b0s = eb2[colA], b1s = eb2[128 + colA];
        #pragma unroll
        for (int mt = 0; mt < 2; ++mt) {
            #pragma unroll
            for (int j = 0; j < 4; ++j) {
                const int row = mt * 16 + kgrp * 4 + j;
                const half4 cc = *(const half4*)(smc + S_B + ((row * 768 + 752) ^ SWZ(row)));
                const float c0 = (float)cc[0] + (float)cc[1];
                const float c1 = (float)cc[2] + (float)cc[3];
                float v = c0 * (cA[mt][j] + b0s) + c1 * (cB[mt][j] + b1s);
                v = fmaxf(v, 0.f);
                *(_Float16*)(smc + H2_B + ((row * 256 + colA * 2) ^ SWZ(row))) = (_Float16)v;
            }
        }
    }
    __syncthreads();

    // ---------- E3 ----------
    if (wv < 4) {
        const int colt = wv & 1;
        const int mt   = wv >> 1;
        f32x4 c0a = {0,0,0,0}, c1a = {0,0,0,0};
        const int col  = colt * 16 + l15;
        const bool vcol = (col < 17);
        const int arow = mt * 16 + l15;
        half8 pb0 = e3a, pb1 = e3b;
        #pragma unroll
        for (int kc = 0; kc < 4; ++kc) {
            const half8 b0 = pb0, b1 = pb1;
            if (kc + 1 < 4) {
                if constexpr (USE_WS) {
                    pb0 = *(const half8*)(wsw + WS_EM + (colt * 4 + kc + 1) * 512 + lB);
                    pb1 = *(const half8*)(wsw + WS_EM + ((2 + colt) * 4 + kc + 1) * 512 + lB);
                } else {
                    const int g = (kc + 1) * 4 + kgrp;
                    pb0 = vcol ? cvt8(ewm + col * 128 + g * 8)        : zf;
                    pb1 = vcol ? cvt8(ewm + (17 + col) * 128 + g * 8) : zf;
                }
            }
            const int koff = kc * 64 + kg16;
            const half8 af = *(const half8*)(smc + H2_B + ((arow * 256 + koff) ^ SWZ(arow)));
            c0a = MFMA16(af, b0, c0a);
            c1a = MFMA16(af, b1, c1a);
        }
        if (vcol) {
            const float b0 = ebm[col], b1 = ebm[17 + col];
            #pragma unroll
            for (int j = 0; j < 4; ++j) {
                const int row = mt * 16 + kgrp * 4 + j;
                const half4 cc = *(const half4*)(smc + S_B + ((row * 768 + 752) ^ SWZ(row)));
                const float c0 = (float)cc[0] + (float)cc[1];
                const float c1 = (float)cc[2] + (float)cc[3];
                const float v = c0 * (c0a[j] + b0) + c1 * (c1a[j] + b1);
                out[(long)(base + row) * 17 + col] = tanhf(v);
            }
        }
    }
}

extern "C" void kernel_launch(void* const* d_in, const int* in_sizes, int n_in,
                              void* d_out, int out_size, void* d_ws, size_t ws_size,
                              hipStream_t stream) {
    (void)in_sizes; (void)n_in; (void)out_size;
    const float* states = (const float*)d_in[0];
    const float* bw1 = (const float*)d_in[1];
    const float* bb1 = (const float*)d_in[2];
    const float* bw2 = (const float*)d_in[3];
    const float* bb2 = (const float*)d_in[4];
    const float* bwo = (const float*)d_in[5];
    const float* bbo = (const float*)d_in[6];
    const float* ew1 = (const float*)d_in[7];
    const float* eb1 = (const float*)d_in[8];
    const float* ew2 = (const float*)d_in[9];
    const float* eb2 = (const float*)d_in[10];
    const float* ewm = (const float*)d_in[11];
    const float* ebm = (const float*)d_in[12];
    float* out = (float*)d_out;

    const int nblk = 65536 / MT;   // 2048

    if (d_ws != nullptr && ws_size >= (size_t)WS_BYTES) {
        _Float16* wsw = (_Float16*)d_ws;
        prep_weights<<<dim3((WS_HALFS + 255) / 256), dim3(256), 0, stream>>>(
            bw1, bw2, ew1, ew2, ewm, wsw);
        actor_kernel<true><<<dim3(nblk), dim3(T), LDS_BYTES, stream>>>(
            states, bw1, bb1, bw2, bb2, bwo, bbo,
            ew1, eb1, ew2, eb2, ewm, ebm, wsw, out);
    } else {
        actor_kernel<false><<<dim3(nblk), dim3(T), LDS_BYTES, stream>>>(
            states, bw1, bb1, bw2, bb2, bwo, bbo,
            ew1, eb1, ew2, eb2, ewm, ebm, nullptr, out);
    }
}

// Round 14
// 96.687 us; speedup vs baseline: 1.0020x; 1.0020x over previous
//
#include <hip/hip_runtime.h>
#include <math.h>

// Fused Actor network via single-term fp16 MFMA. Round 14: r12 + waves_per_eu(6).
// r13 post-mortem: cross-barrier pre-issue raised live ranges -> 68 arch + AGPR > 128
// -> 1 block/CU (23% occ) -> regression. Reverted.
// r12 analysis: resident waves issue ~41% of slots at 41% occupancy -> occupancy-limited.
// MT=32 LDS (40960B) admits 3 blocks/CU; gate is regs: 6 waves/SIMD needs <=85 total.
// r12 footprint ~56 arch + 32 acc = 88 -> waves_per_eu(6) asks the allocator for the
// ~3-reg shave. Single change vs r12 (86.8us): (2) -> (6).
// Block = 32 samples, 512 threads = 8 waves. Weights pre-tiled in d_ws (1KB bursts).
// LDS XOR-swizzle: byte ^= (row&7)<<4.

typedef __attribute__((ext_vector_type(8))) _Float16 half8;
typedef __attribute__((ext_vector_type(4))) _Float16 half4;
typedef __attribute__((ext_vector_type(4))) float    f32x4;

#define MFMA16(a, b, c) __builtin_amdgcn_mfma_f32_16x16x32_f16((a), (b), (c), 0, 0, 0)
#define SWZ(row) (((row) & 7) << 4)

#define MT 32
#define T  512

// ---- LDS byte offsets (total 40,960 B) ----
// S  [0, 24576): 32 rows x 384 f16 (stride 768B); cols 376..383 zero-padded;
//    after A3 pad bytes 752..759 hold (c0h,c0l,c1h,c1l) fp16 per row.
// G1 [24576, 32768): 32x128 f16 (stride 256B)
// G2 [32768, 40960): 32x128 f16
// H1 [24576, 40960): 32x256 f16 (stride 512B), overlays G1+G2
// H2 [24576, 32768): 32x128 f16, overlays H1 low half (barrier between read + write)
#define S_B      0
#define G1_B     24576
#define G2_B     32768
#define H1_B     24576
#define H2_B     24576
#define LDS_BYTES 40960

// ---- ws half-element offsets; tiled layout: tile(n0,kc) at ((n0*KC+kc)*512), [lane][8] ----
#define WS_W1 0        /* bw1: N0=8,  KC=12 -> 49152 halfs */
#define WS_W2 49152    /* bw2: N0=8,  KC=4  -> 16384 */
#define WS_E1 65536    /* ew1: N0=32, KC=12 -> 196608 */
#define WS_E2 262144   /* ew2: N0=16, KC=8  -> 65536 */
#define WS_EM 327680   /* ewm: N0=4,  KC=4  -> 8192 (2 experts x 32 rows padded) */
#define WS_HALFS 335872
#define WS_BYTES 671744

__device__ __forceinline__ half8 cvt8(const float* __restrict__ p) {
    const float4 a = *reinterpret_cast<const float4*>(p);
    const float4 b = *reinterpret_cast<const float4*>(p + 4);
    half8 r;
    r[0] = (_Float16)a.x; r[1] = (_Float16)a.y; r[2] = (_Float16)a.z; r[3] = (_Float16)a.w;
    r[4] = (_Float16)b.x; r[5] = (_Float16)b.y; r[6] = (_Float16)b.z; r[7] = (_Float16)b.w;
    return r;
}

// ================= prep kernel: fp32 weights -> fp16 B-fragment tiles in ws =================
// For a matrix W[N][K]: tile t = n0*KC + kc; within tile, half index = l*8 + j maps to
// n = n0*16 + (l&15), k = kc*32 + (l>>4)*8 + j. Out-of-range (n,k) -> 0.
__global__ __launch_bounds__(256)
void prep_weights(const float* __restrict__ bw1, const float* __restrict__ bw2,
                  const float* __restrict__ ew1, const float* __restrict__ ew2,
                  const float* __restrict__ ewm, _Float16* __restrict__ wsw)
{
    const int i = blockIdx.x * 256 + threadIdx.x;
    if (i >= WS_HALFS) return;
    const float* W; int N, K, KC, j0;
    if      (i < 49152)  { W = bw1; N = 128; K = 376; KC = 12; j0 = i - WS_W1; }
    else if (i < 65536)  { W = bw2; N = 128; K = 128; KC = 4;  j0 = i - WS_W2; }
    else if (i < 262144) { W = ew1; N = 512; K = 376; KC = 12; j0 = i - WS_E1; }
    else if (i < 327680) { W = ew2; N = 256; K = 256; KC = 8;  j0 = i - WS_E2; }
    else                 { W = ewm; N = 34;  K = 128; KC = 4;  j0 = i - WS_EM; }
    const int tile = j0 >> 9;
    const int rem  = j0 & 511;
    const int l    = rem >> 3;
    const int jj   = rem & 7;
    const int n0   = tile / KC, kc = tile - n0 * KC;
    int n = n0 * 16 + (l & 15);
    const int k = kc * 32 + (l >> 4) * 8 + jj;
    float v = 0.f;
    if (W == ewm) {  // ewm logical rows: 2 experts x 32 padded rows -> src 2 x 17
        const int e = n >> 5, a = n & 31;
        if (a < 17 && k < K) v = ewm[(e * 17 + a) * K + k];
    } else {
        if (n < N && k < K) v = W[n * K + k];
    }
    wsw[i] = (_Float16)v;
}

// ================= fused actor kernel =================
template <bool USE_WS>
__global__ __launch_bounds__(512)
__attribute__((amdgpu_waves_per_eu(6)))
void actor_kernel(const float* __restrict__ states,
                  const float* __restrict__ bw1, const float* __restrict__ bb1,
                  const float* __restrict__ bw2, const float* __restrict__ bb2,
                  const float* __restrict__ bwo, const float* __restrict__ bbo,
                  const float* __restrict__ ew1, const float* __restrict__ eb1,
                  const float* __restrict__ ew2, const float* __restrict__ eb2,
                  const float* __restrict__ ewm, const float* __restrict__ ebm,
                  const _Float16* __restrict__ wsw,
                  float* __restrict__ out)
{
    extern __shared__ char smc[];
    const int t    = threadIdx.x;
    const int l    = t & 63;
    const int l15  = l & 15;
    const int kgrp = l >> 4;          // 0..3
    const int kg16 = kgrp * 16;       // byte offset within a 32-col (64B) chunk
    const int wv   = __builtin_amdgcn_readfirstlane(t >> 6);
    const int base = blockIdx.x * MT;
    const int lB   = l * 8;           // half offset of this lane's frag within a ws tile

    const half8 zf = {0,0,0,0,0,0,0,0};

    // ---------- stage: states fp32 -> fp16 in LDS (swizzled) ----------
    {
        const float4* src = reinterpret_cast<const float4*>(states + (long)base * 376);
        for (int q = t; q < MT * 94; q += T) {
            const int r  = q / 94;
            const int c4 = q - r * 94;
            const float4 v = src[q];
            half4 h;
            h[0] = (_Float16)v.x; h[1] = (_Float16)v.y;
            h[2] = (_Float16)v.z; h[3] = (_Float16)v.w;
            *(half4*)(smc + S_B + ((r * 768 + c4 * 8) ^ SWZ(r))) = h;
        }
        if (t < MT) {  // zero K-pad cols 376..383 (bytes 752..768)
            *(float4*)(smc + S_B + ((t * 768 + 752) ^ SWZ(t))) = make_float4(0.f, 0.f, 0.f, 0.f);
        }
    }
    __syncthreads();

    // ---------- A1: G1 = relu(S @ bw1^T + bb1)  M=32 N=128 K=384 ----------
    {
        f32x4 acc[2] = {{0,0,0,0},{0,0,0,0}};
        const int col = wv * 16 + l15;
        auto ldW = [&](int kc) -> half8 {
            if constexpr (USE_WS) return *(const half8*)(wsw + WS_W1 + (wv * 12 + kc) * 512 + lB);
            else { const int g = kc * 4 + kgrp; return (g < 47) ? cvt8(bw1 + col * 376 + g * 8) : zf; }
        };
        half8 bf = ldW(0);
        #pragma unroll
        for (int kc = 0; kc < 12; ++kc) {
            const half8 cur = bf;
            if (kc < 11) bf = ldW(kc + 1);
            const int koff = kc * 64 + kg16;
            #pragma unroll
            for (int mt = 0; mt < 2; ++mt) {
                const int row = mt * 16 + l15;
                const half8 af = *(const half8*)(smc + S_B + ((row * 768 + koff) ^ SWZ(row)));
                acc[mt] = MFMA16(af, cur, acc[mt]);
            }
        }
        const float bias = bb1[col];
        #pragma unroll
        for (int mt = 0; mt < 2; ++mt) {
            #pragma unroll
            for (int j = 0; j < 4; ++j) {
                const int row = mt * 16 + kgrp * 4 + j;
                const float v = fmaxf(acc[mt][j] + bias, 0.f);
                *(_Float16*)(smc + G1_B + ((row * 256 + col * 2) ^ SWZ(row))) = (_Float16)v;
            }
        }
    }
    __syncthreads();

    // ---------- A2: G2 = relu(G1 @ bw2^T + bb2)  M=32 N=128 K=128 ----------
    {
        f32x4 acc[2] = {{0,0,0,0},{0,0,0,0}};
        const int col = wv * 16 + l15;
        auto ldW = [&](int kc) -> half8 {
            if constexpr (USE_WS) return *(const half8*)(wsw + WS_W2 + (wv * 4 + kc) * 512 + lB);
            else                  return cvt8(bw2 + col * 128 + (kc * 4 + kgrp) * 8);
        };
        half8 bf = ldW(0);
        #pragma unroll
        for (int kc = 0; kc < 4; ++kc) {
            const half8 cur = bf;
            if (kc < 3) bf = ldW(kc + 1);
            const int koff = kc * 64 + kg16;
            #pragma unroll
            for (int mt = 0; mt < 2; ++mt) {
                const int row = mt * 16 + l15;
                const half8 af = *(const half8*)(smc + G1_B + ((row * 256 + koff) ^ SWZ(row)));
                acc[mt] = MFMA16(af, cur, acc[mt]);
            }
        }
        const float bias = bb2[col];
        #pragma unroll
        for (int mt = 0; mt < 2; ++mt) {
            #pragma unroll
            for (int j = 0; j < 4; ++j) {
                const int row = mt * 16 + kgrp * 4 + j;
                const float v = fmaxf(acc[mt][j] + bias, 0.f);
                *(_Float16*)(smc + G2_B + ((row * 256 + col * 2) ^ SWZ(row))) = (_Float16)v;
            }
        }
    }
    __syncthreads();

    // ---------- A3: softmax coeffs, all 512 threads ----------
    // thread -> (sample s = t>>4, r = t&15: expert e = r&1, k-chunk = r>>1 of 16 k each);
    // shfl-xor reduce chunks (masks 2,4,8 stay within the 16-thread sample group).
    {
        const int s     = t >> 4;
        const int r     = t & 15;
        const int e     = r & 1;
        const int chunk = r >> 1;
        float z = 0.f;
        const float* wo = bwo + e * 128 + chunk * 16;
        #pragma unroll
        for (int q = 0; q < 2; ++q) {
            const half8 hv = *(const half8*)(smc + G2_B + ((s * 256 + chunk * 32 + q * 16) ^ SWZ(s)));
            const float4 w0 = *(const float4*)(wo + q * 8);
            const float4 w1 = *(const float4*)(wo + q * 8 + 4);
            z = fmaf((float)hv[0], w0.x, z); z = fmaf((float)hv[1], w0.y, z);
            z = fmaf((float)hv[2], w0.z, z); z = fmaf((float)hv[3], w0.w, z);
            z = fmaf((float)hv[4], w1.x, z); z = fmaf((float)hv[5], w1.y, z);
            z = fmaf((float)hv[6], w1.z, z); z = fmaf((float)hv[7], w1.w, z);
        }
        z += __shfl_xor(z, 2, 64);
        z += __shfl_xor(z, 4, 64);
        z += __shfl_xor(z, 8, 64);
        z += bbo[e];
        const float zo = __shfl_xor(z, 1, 64);   // other expert's logit
        if (r < 2) {
            const float m = fmaxf(z, zo);
            const float ea = __expf(z - m), eb = __expf(zo - m);
            const float c_self = ea / (ea + eb);
            const _Float16 ch = (_Float16)c_self;
            const _Float16 cl = (_Float16)(c_self - (float)ch);
            union { _Float16 h[2]; unsigned u; } pk;
            pk.h[0] = ch; pk.h[1] = cl;
            *(unsigned*)(smc + S_B + (((s * 768 + 752) ^ SWZ(s)) + e * 4)) = pk.u;
        }
    }
    __syncthreads();

    // ---------- E1: H1 = relu(blend(S @ ew1[e]^T + eb1[e]))  M=32 N=256x2 K=384 ----------
    {
        f32x4 aA[2][2], aB[2][2];   // [nt][mt]
        #pragma unroll
        for (int nt = 0; nt < 2; ++nt)
            #pragma unroll
            for (int mt = 0; mt < 2; ++mt) { aA[nt][mt] = {0,0,0,0}; aB[nt][mt] = {0,0,0,0}; }

        auto ldE1 = [&](int kc, int nt, int ex) -> half8 {
            if constexpr (USE_WS) {
                const int n0 = wv * 2 + nt + ex * 16;
                return *(const half8*)(wsw + WS_E1 + (n0 * 12 + kc) * 512 + lB);
            } else {
                const int g = kc * 4 + kgrp;
                const int wr = wv * 32 + nt * 16 + l15 + ex * 256;
                return (g < 47) ? cvt8(ew1 + wr * 376 + g * 8) : zf;
            }
        };
        half8 b00 = ldE1(0, 0, 0), b01 = ldE1(0, 0, 1);
        half8 b10 = ldE1(0, 1, 0), b11 = ldE1(0, 1, 1);
        #pragma unroll
        for (int kc = 0; kc < 12; ++kc) {
            const half8 c00 = b00, c01 = b01, c10 = b10, c11 = b11;
            if (kc < 11) {
                b00 = ldE1(kc + 1, 0, 0); b01 = ldE1(kc + 1, 0, 1);
                b10 = ldE1(kc + 1, 1, 0); b11 = ldE1(kc + 1, 1, 1);
            }
            const int koff = kc * 64 + kg16;
            #pragma unroll
            for (int mt = 0; mt < 2; ++mt) {
                const int row = mt * 16 + l15;
                const half8 af = *(const half8*)(smc + S_B + ((row * 768 + koff) ^ SWZ(row)));
                aA[0][mt] = MFMA16(af, c00, aA[0][mt]);
                aB[0][mt] = MFMA16(af, c01, aB[0][mt]);
                aA[1][mt] = MFMA16(af, c10, aA[1][mt]);
                aB[1][mt] = MFMA16(af, c11, aB[1][mt]);
            }
        }
        #pragma unroll
        for (int nt = 0; nt < 2; ++nt) {
            const int col = wv * 32 + nt * 16 + l15;
            const float b0 = eb1[col], b1 = eb1[256 + col];
            #pragma unroll
            for (int mt = 0; mt < 2; ++mt) {
                #pragma unroll
                for (int j = 0; j < 4; ++j) {
                    const int row = mt * 16 + kgrp * 4 + j;
                    const half4 cc = *(const half4*)(smc + S_B + ((row * 768 + 752) ^ SWZ(row)));
                    const float c0 = (float)cc[0] + (float)cc[1];
                    const float c1 = (float)cc[2] + (float)cc[3];
                    float v = c0 * (aA[nt][mt][j] + b0) + c1 * (aB[nt][mt][j] + b1);
                    v = fmaxf(v, 0.f);
                    *(_Float16*)(smc + H1_B + ((row * 512 + col * 2) ^ SWZ(row))) = (_Float16)v;
                }
            }
        }
    }
    __syncthreads();

    // ---------- E2: H2 = relu(blend(H1 @ ew2[e]^T + eb2[e]))  M=32 N=128x2 K=256 ----------
    {
        f32x4 cA[2], cB[2];
        #pragma unroll
        for (int mt = 0; mt < 2; ++mt) { cA[mt] = {0,0,0,0}; cB[mt] = {0,0,0,0}; }
        const int col = wv * 16 + l15;
        auto ldE2 = [&](int kc, int ex) -> half8 {
            if constexpr (USE_WS) {
                return *(const half8*)(wsw + WS_E2 + ((wv + ex * 8) * 8 + kc) * 512 + lB);
            } else {
                const int g = kc * 4 + kgrp;
                return cvt8(ew2 + (col + ex * 128) * 256 + g * 8);
            }
        };
        half8 b0 = ldE2(0, 0), b1 = ldE2(0, 1);
        #pragma unroll
        for (int kc = 0; kc < 8; ++kc) {
            const half8 c0f = b0, c1f = b1;
            if (kc < 7) { b0 = ldE2(kc + 1, 0); b1 = ldE2(kc + 1, 1); }
            const int koff = kc * 64 + kg16;
            #pragma unroll
            for (int mt = 0; mt < 2; ++mt) {
                const int row = mt * 16 + l15;
                const half8 af = *(const half8*)(smc + H1_B + ((row * 512 + koff) ^ SWZ(row)));
                cA[mt] = MFMA16(af, c0f, cA[mt]);
                cB[mt] = MFMA16(af, c1f, cB[mt]);
            }
        }
        __syncthreads();   // all H1 reads done before H2 overlays H1 low half
        const float b0s = eb2[col], b1s = eb2[128 + col];
        #pragma unroll
        for (int mt = 0; mt < 2; ++mt) {
            #pragma unroll
            for (int j = 0; j < 4; ++j) {
                const int row = mt * 16 + kgrp * 4 + j;
                const half4 cc = *(const half4*)(smc + S_B + ((row * 768 + 752) ^ SWZ(row)));
                const float c0 = (float)cc[0] + (float)cc[1];
                const float c1 = (float)cc[2] + (float)cc[3];
                float v = c0 * (cA[mt][j] + b0s) + c1 * (cB[mt][j] + b1s);
                v = fmaxf(v, 0.f);
                *(_Float16*)(smc + H2_B + ((row * 256 + col * 2) ^ SWZ(row))) = (_Float16)v;
            }
        }
    }
    __syncthreads();

    // ---------- E3: mu = tanh(blend(H2 @ ewm[e]^T + ebm[e]))  M=32 N=17x2 K=128 ----------
    if (wv < 4) {
        const int colt = wv & 1;      // col tile (2x16 covers 17)
        const int mt   = wv >> 1;     // row tile
        f32x4 c0a = {0,0,0,0}, c1a = {0,0,0,0};
        const int col  = colt * 16 + l15;
        const bool vcol = (col < 17);
        const int arow = mt * 16 + l15;
        for (int kc = 0; kc < 4; ++kc) {
            const int koff = kc * 64 + kg16;
            const half8 af = *(const half8*)(smc + H2_B + ((arow * 256 + koff) ^ SWZ(arow)));
            half8 b0, b1;
            if constexpr (USE_WS) {
                b0 = *(const half8*)(wsw + WS_EM + (colt * 4 + kc) * 512 + lB);
                b1 = *(const half8*)(wsw + WS_EM + ((2 + colt) * 4 + kc) * 512 + lB);
            } else {
                const int g = kc * 4 + kgrp;
                b0 = vcol ? cvt8(ewm + col * 128 + g * 8)        : zf;
                b1 = vcol ? cvt8(ewm + (17 + col) * 128 + g * 8) : zf;
            }
            c0a = MFMA16(af, b0, c0a);
            c1a = MFMA16(af, b1, c1a);
        }
        if (vcol) {
            const float b0 = ebm[col], b1 = ebm[17 + col];
            #pragma unroll
            for (int j = 0; j < 4; ++j) {
                const int row = mt * 16 + kgrp * 4 + j;
                const half4 cc = *(const half4*)(smc + S_B + ((row * 768 + 752) ^ SWZ(row)));
                const float c0 = (float)cc[0] + (float)cc[1];
                const float c1 = (float)cc[2] + (float)cc[3];
                const float v = c0 * (c0a[j] + b0) + c1 * (c1a[j] + b1);
                out[(long)(base + row) * 17 + col] = tanhf(v);
            }
        }
    }
}

extern "C" void kernel_launch(void* const* d_in, const int* in_sizes, int n_in,
                              void* d_out, int out_size, void* d_ws, size_t ws_size,
                              hipStream_t stream) {
    (void)in_sizes; (void)n_in; (void)out_size;
    const float* states = (const float*)d_in[0];
    const float* bw1 = (const float*)d_in[1];
    const float* bb1 = (const float*)d_in[2];
    const float* bw2 = (const float*)d_in[3];
    const float* bb2 = (const float*)d_in[4];
    const float* bwo = (const float*)d_in[5];
    const float* bbo = (const float*)d_in[6];
    const float* ew1 = (const float*)d_in[7];
    const float* eb1 = (const float*)d_in[8];
    const float* ew2 = (const float*)d_in[9];
    const float* eb2 = (const float*)d_in[10];
    const float* ewm = (const float*)d_in[11];
    const float* ebm = (const float*)d_in[12];
    float* out = (float*)d_out;

    const int nblk = 65536 / MT;   // 2048

    if (d_ws != nullptr && ws_size >= (size_t)WS_BYTES) {
        _Float16* wsw = (_Float16*)d_ws;
        prep_weights<<<dim3((WS_HALFS + 255) / 256), dim3(256), 0, stream>>>(
            bw1, bw2, ew1, ew2, ewm, wsw);
        actor_kernel<true><<<dim3(nblk), dim3(T), LDS_BYTES, stream>>>(
            states, bw1, bb1, bw2, bb2, bwo, bbo,
            ew1, eb1, ew2, eb2, ewm, ebm, wsw, out);
    } else {
        actor_kernel<false><<<dim3(nblk), dim3(T), LDS_BYTES, stream>>>(
            states, bw1, bb1, bw2, bb2, bwo, bbo,
            ew1, eb1, ew2, eb2, ewm, ebm, nullptr, out);
    }
}

// Round 15
// 84.452 us; speedup vs baseline: 1.1472x; 1.1449x over previous
//
#include <hip/hip_runtime.h>
#include <math.h>

// Fused Actor network via single-term fp16 MFMA. Round 15: r12 (86.8us) + VALU diet.
// r14 resolved the occupancy model: MFMA accs occupy a 64-AGPR granule; waves/SIMD =
// floor(512/(arch+64)) -> 4 waves needs arch<=64 (r12: 56 ok), 5 waves needs arch<=38
// (guaranteed spill). r12 is the occupancy optimum; its counters (busy 41% = occupancy
// 41%) show resident waves issue ~every cycle -> ISSUE-SLOT-BOUND -> cut VALU count:
//  (1) bias folded into K-pad col 376 (S col376=1.0, prep writes bias at k=376) for A1/E1
//  (2) coeffs stored f32 in dedicated CF buffer (NOT in MFMA-read pad: f32 bits as fp16
//      can be NaN; NaN*0=NaN) -> epilogue reads float2, zero cvt/add
//  (3) fast tanh via __expf identity
// Block = 32 samples, 512 threads = 8 waves, LDS 41,216 B -> 2 blocks/CU.
// Weights pre-tiled in d_ws as B-fragment tiles (per-wave 1KB bursts); depth-1 prefetch.
// LDS XOR-swizzle: byte ^= (row&7)<<4.

typedef __attribute__((ext_vector_type(8))) _Float16 half8;
typedef __attribute__((ext_vector_type(4))) _Float16 half4;
typedef __attribute__((ext_vector_type(4))) float    f32x4;

#define MFMA16(a, b, c) __builtin_amdgcn_mfma_f32_16x16x32_f16((a), (b), (c), 0, 0, 0)
#define SWZ(row) (((row) & 7) << 4)

#define MT 32
#define T  512

// ---- LDS byte offsets (total 41,216 B) ----
// S  [0, 24576): 32 rows x 384 f16 (stride 768B); col 376 = 1.0 (bias lane), 377..383 = 0.
// G1 [24576, 32768): 32x128 f16 (stride 256B)
// G2 [32768, 40960): 32x128 f16
// H1 [24576, 40960): 32x256 f16 (stride 512B), overlays G1+G2
// H2 [24576, 32768): 32x128 f16, overlays H1 low half (barrier between read + write)
// CF [40960, 41216): 32 x (c0,c1) f32
#define S_B      0
#define G1_B     24576
#define G2_B     32768
#define H1_B     24576
#define H2_B     24576
#define CF_B     40960
#define LDS_BYTES 41216

// ---- ws half-element offsets; tiled layout: tile(n0,kc) at ((n0*KC+kc)*512), [lane][8] ----
#define WS_W1 0        /* bw1: N0=8,  KC=12 -> 49152 halfs (k=376 holds bb1) */
#define WS_W2 49152    /* bw2: N0=8,  KC=4  -> 16384 */
#define WS_E1 65536    /* ew1: N0=32, KC=12 -> 196608 (k=376 holds eb1) */
#define WS_E2 262144   /* ew2: N0=16, KC=8  -> 65536 */
#define WS_EM 327680   /* ewm: N0=4,  KC=4  -> 8192 (2 experts x 32 rows padded) */
#define WS_HALFS 335872
#define WS_BYTES 671744

__device__ __forceinline__ half8 cvt8(const float* __restrict__ p) {
    const float4 a = *reinterpret_cast<const float4*>(p);
    const float4 b = *reinterpret_cast<const float4*>(p + 4);
    half8 r;
    r[0] = (_Float16)a.x; r[1] = (_Float16)a.y; r[2] = (_Float16)a.z; r[3] = (_Float16)a.w;
    r[4] = (_Float16)b.x; r[5] = (_Float16)b.y; r[6] = (_Float16)b.z; r[7] = (_Float16)b.w;
    return r;
}

// ================= prep kernel: fp32 weights -> fp16 B-fragment tiles in ws =================
// For W[N][K]: tile t = n0*KC + kc; half index = l*8 + j -> n = n0*16 + (l&15),
// k = kc*32 + (l>>4)*8 + j. k==K (=376 pad col) -> bias; other out-of-range -> 0.
__global__ __launch_bounds__(256)
void prep_weights(const float* __restrict__ bw1, const float* __restrict__ bb1,
                  const float* __restrict__ bw2,
                  const float* __restrict__ ew1, const float* __restrict__ eb1,
                  const float* __restrict__ ew2,
                  const float* __restrict__ ewm, _Float16* __restrict__ wsw)
{
    const int i = blockIdx.x * 256 + threadIdx.x;
    if (i >= WS_HALFS) return;
    int sec; const float* W; const float* Bv; int N, K, KC, j0;
    if      (i < 49152)  { sec = 0; W = bw1; Bv = bb1;    N = 128; K = 376; KC = 12; j0 = i - WS_W1; }
    else if (i < 65536)  { sec = 1; W = bw2; Bv = nullptr; N = 128; K = 128; KC = 4;  j0 = i - WS_W2; }
    else if (i < 262144) { sec = 2; W = ew1; Bv = eb1;    N = 512; K = 376; KC = 12; j0 = i - WS_E1; }
    else if (i < 327680) { sec = 3; W = ew2; Bv = nullptr; N = 256; K = 256; KC = 8;  j0 = i - WS_E2; }
    else                 { sec = 4; W = ewm; Bv = nullptr; N = 34;  K = 128; KC = 4;  j0 = i - WS_EM; }
    const int tile = j0 >> 9;
    const int rem  = j0 & 511;
    const int l    = rem >> 3;
    const int jj   = rem & 7;
    const int n0   = tile / KC, kc = tile - n0 * KC;
    const int n = n0 * 16 + (l & 15);
    const int k = kc * 32 + (l >> 4) * 8 + jj;
    float v = 0.f;
    if (sec == 4) {  // ewm logical rows: 2 experts x 32 padded rows -> src 2 x 17
        const int e = n >> 5, a = n & 31;
        if (a < 17 && k < K) v = ewm[(e * 17 + a) * K + k];
    } else if (n < N) {
        if (k < K)                 v = W[n * K + k];
        else if (k == K && Bv)     v = Bv[n];       // bias rides pad col k==376
    }
    wsw[i] = (_Float16)v;
}

// ================= fused actor kernel =================
template <bool USE_WS>
__global__ __launch_bounds__(512)
__attribute__((amdgpu_waves_per_eu(2)))
void actor_kernel(const float* __restrict__ states,
                  const float* __restrict__ bw1, const float* __restrict__ bb1,
                  const float* __restrict__ bw2, const float* __restrict__ bb2,
                  const float* __restrict__ bwo, const float* __restrict__ bbo,
                  const float* __restrict__ ew1, const float* __restrict__ eb1,
                  const float* __restrict__ ew2, const float* __restrict__ eb2,
                  const float* __restrict__ ewm, const float* __restrict__ ebm,
                  const _Float16* __restrict__ wsw,
                  float* __restrict__ out)
{
    extern __shared__ char smc[];
    const int t    = threadIdx.x;
    const int l    = t & 63;
    const int l15  = l & 15;
    const int kgrp = l >> 4;          // 0..3
    const int kg16 = kgrp * 16;       // byte offset within a 32-col (64B) chunk
    const int wv   = __builtin_amdgcn_readfirstlane(t >> 6);
    const int base = blockIdx.x * MT;
    const int lB   = l * 8;           // half offset of this lane's frag within a ws tile

    const half8 zf = {0,0,0,0,0,0,0,0};

    // ---------- stage: states fp32 -> fp16 in LDS (swizzled) ----------
    {
        const float4* src = reinterpret_cast<const float4*>(states + (long)base * 376);
        for (int q = t; q < MT * 94; q += T) {
            const int r  = q / 94;
            const int c4 = q - r * 94;
            const float4 v = src[q];
            half4 h;
            h[0] = (_Float16)v.x; h[1] = (_Float16)v.y;
            h[2] = (_Float16)v.z; h[3] = (_Float16)v.w;
            *(half4*)(smc + S_B + ((r * 768 + c4 * 8) ^ SWZ(r))) = h;
        }
        if (t < MT) {  // pad cols 376..383: col 376 = 1.0 (bias lane), rest 0
            const int off = (t * 768 + 752) ^ SWZ(t);
            *(ushort4*)(smc + S_B + off)     = make_ushort4(0x3C00u, 0, 0, 0);
            *(ushort4*)(smc + S_B + off + 8) = make_ushort4(0, 0, 0, 0);
        }
    }
    __syncthreads();

    // ---------- A1: G1 = relu(S @ bw1^T [+ bb1 via pad])  M=32 N=128 K=384 ----------
    {
        f32x4 acc[2] = {{0,0,0,0},{0,0,0,0}};
        const int col = wv * 16 + l15;
        auto ldW = [&](int kc) -> half8 {
            if constexpr (USE_WS) return *(const half8*)(wsw + WS_W1 + (wv * 12 + kc) * 512 + lB);
            else {
                const int g = kc * 4 + kgrp;
                if (g < 47) return cvt8(bw1 + col * 376 + g * 8);
                half8 rr = zf; rr[0] = (_Float16)bb1[col]; return rr;   // g==47: k=376 bias
            }
        };
        half8 bf = ldW(0);
        #pragma unroll
        for (int kc = 0; kc < 12; ++kc) {
            const half8 cur = bf;
            if (kc < 11) bf = ldW(kc + 1);
            const int koff = kc * 64 + kg16;
            #pragma unroll
            for (int mt = 0; mt < 2; ++mt) {
                const int row = mt * 16 + l15;
                const half8 af = *(const half8*)(smc + S_B + ((row * 768 + koff) ^ SWZ(row)));
                acc[mt] = MFMA16(af, cur, acc[mt]);
            }
        }
        #pragma unroll
        for (int mt = 0; mt < 2; ++mt) {
            #pragma unroll
            for (int j = 0; j < 4; ++j) {
                const int row = mt * 16 + kgrp * 4 + j;
                const float v = fmaxf(acc[mt][j], 0.f);   // bias already in acc
                *(_Float16*)(smc + G1_B + ((row * 256 + col * 2) ^ SWZ(row))) = (_Float16)v;
            }
        }
    }
    __syncthreads();

    // ---------- A2: G2 = relu(G1 @ bw2^T + bb2)  M=32 N=128 K=128 ----------
    {
        f32x4 acc[2] = {{0,0,0,0},{0,0,0,0}};
        const int col = wv * 16 + l15;
        auto ldW = [&](int kc) -> half8 {
            if constexpr (USE_WS) return *(const half8*)(wsw + WS_W2 + (wv * 4 + kc) * 512 + lB);
            else                  return cvt8(bw2 + col * 128 + (kc * 4 + kgrp) * 8);
        };
        half8 bf = ldW(0);
        #pragma unroll
        for (int kc = 0; kc < 4; ++kc) {
            const half8 cur = bf;
            if (kc < 3) bf = ldW(kc + 1);
            const int koff = kc * 64 + kg16;
            #pragma unroll
            for (int mt = 0; mt < 2; ++mt) {
                const int row = mt * 16 + l15;
                const half8 af = *(const half8*)(smc + G1_B + ((row * 256 + koff) ^ SWZ(row)));
                acc[mt] = MFMA16(af, cur, acc[mt]);
            }
        }
        const float bias = bb2[col];
        #pragma unroll
        for (int mt = 0; mt < 2; ++mt) {
            #pragma unroll
            for (int j = 0; j < 4; ++j) {
                const int row = mt * 16 + kgrp * 4 + j;
                const float v = fmaxf(acc[mt][j] + bias, 0.f);
                *(_Float16*)(smc + G2_B + ((row * 256 + col * 2) ^ SWZ(row))) = (_Float16)v;
            }
        }
    }
    __syncthreads();

    // ---------- A3: softmax coeffs -> f32 (c0,c1) in CF, all 512 threads ----------
    // thread -> (sample s = t>>4, r = t&15: expert e = r&1, k-chunk = r>>1 of 16 k each);
    // shfl-xor reduce chunks (masks 2,4,8 stay within the 16-thread sample group).
    {
        const int s     = t >> 4;
        const int r     = t & 15;
        const int e     = r & 1;
        const int chunk = r >> 1;
        float z = 0.f;
        const float* wo = bwo + e * 128 + chunk * 16;
        #pragma unroll
        for (int q = 0; q < 2; ++q) {
            const half8 hv = *(const half8*)(smc + G2_B + ((s * 256 + chunk * 32 + q * 16) ^ SWZ(s)));
            const float4 w0 = *(const float4*)(wo + q * 8);
            const float4 w1 = *(const float4*)(wo + q * 8 + 4);
            z = fmaf((float)hv[0], w0.x, z); z = fmaf((float)hv[1], w0.y, z);
            z = fmaf((float)hv[2], w0.z, z); z = fmaf((float)hv[3], w0.w, z);
            z = fmaf((float)hv[4], w1.x, z); z = fmaf((float)hv[5], w1.y, z);
            z = fmaf((float)hv[6], w1.z, z); z = fmaf((float)hv[7], w1.w, z);
        }
        z += __shfl_xor(z, 2, 64);
        z += __shfl_xor(z, 4, 64);
        z += __shfl_xor(z, 8, 64);
        z += bbo[e];
        const float zo = __shfl_xor(z, 1, 64);   // other expert's logit
        if (r < 2) {
            const float m = fmaxf(z, zo);
            const float ea = __expf(z - m), eb = __expf(zo - m);
            *(float*)(smc + CF_B + s * 8 + e * 4) = ea / (ea + eb);
        }
    }
    __syncthreads();

    // ---------- E1: H1 = relu(blend(S @ ew1[e]^T [+ eb1 via pad]))  M=32 N=256x2 K=384 ----------
    {
        f32x4 aA[2][2], aB[2][2];   // [nt][mt]
        #pragma unroll
        for (int nt = 0; nt < 2; ++nt)
            #pragma unroll
            for (int mt = 0; mt < 2; ++mt) { aA[nt][mt] = {0,0,0,0}; aB[nt][mt] = {0,0,0,0}; }

        auto ldE1 = [&](int kc, int nt, int ex) -> half8 {
            if constexpr (USE_WS) {
                const int n0 = wv * 2 + nt + ex * 16;
                return *(const half8*)(wsw + WS_E1 + (n0 * 12 + kc) * 512 + lB);
            } else {
                const int g = kc * 4 + kgrp;
                const int wr = wv * 32 + nt * 16 + l15 + ex * 256;
                if (g < 47) return cvt8(ew1 + wr * 376 + g * 8);
                half8 rr = zf; rr[0] = (_Float16)eb1[wr]; return rr;    // g==47: k=376 bias
            }
        };
        half8 b00 = ldE1(0, 0, 0), b01 = ldE1(0, 0, 1);
        half8 b10 = ldE1(0, 1, 0), b11 = ldE1(0, 1, 1);
        #pragma unroll
        for (int kc = 0; kc < 12; ++kc) {
            const half8 c00 = b00, c01 = b01, c10 = b10, c11 = b11;
            if (kc < 11) {
                b00 = ldE1(kc + 1, 0, 0); b01 = ldE1(kc + 1, 0, 1);
                b10 = ldE1(kc + 1, 1, 0); b11 = ldE1(kc + 1, 1, 1);
            }
            const int koff = kc * 64 + kg16;
            #pragma unroll
            for (int mt = 0; mt < 2; ++mt) {
                const int row = mt * 16 + l15;
                const half8 af = *(const half8*)(smc + S_B + ((row * 768 + koff) ^ SWZ(row)));
                aA[0][mt] = MFMA16(af, c00, aA[0][mt]);
                aB[0][mt] = MFMA16(af, c01, aB[0][mt]);
                aA[1][mt] = MFMA16(af, c10, aA[1][mt]);
                aB[1][mt] = MFMA16(af, c11, aB[1][mt]);
            }
        }
        #pragma unroll
        for (int nt = 0; nt < 2; ++nt) {
            const int col = wv * 32 + nt * 16 + l15;
            #pragma unroll
            for (int mt = 0; mt < 2; ++mt) {
                #pragma unroll
                for (int j = 0; j < 4; ++j) {
                    const int row = mt * 16 + kgrp * 4 + j;
                    const float2 cc = *(const float2*)(smc + CF_B + row * 8);
                    const float v = fmaxf(cc.x * aA[nt][mt][j] + cc.y * aB[nt][mt][j], 0.f);
                    *(_Float16*)(smc + H1_B + ((row * 512 + col * 2) ^ SWZ(row))) = (_Float16)v;
                }
            }
        }
    }
    __syncthreads();

    // ---------- E2: H2 = relu(blend(H1 @ ew2[e]^T + eb2[e]))  M=32 N=128x2 K=256 ----------
    {
        f32x4 cA[2], cB[2];
        #pragma unroll
        for (int mt = 0; mt < 2; ++mt) { cA[mt] = {0,0,0,0}; cB[mt] = {0,0,0,0}; }
        const int col = wv * 16 + l15;
        auto ldE2 = [&](int kc, int ex) -> half8 {
            if constexpr (USE_WS) {
                return *(const half8*)(wsw + WS_E2 + ((wv + ex * 8) * 8 + kc) * 512 + lB);
            } else {
                const int g = kc * 4 + kgrp;
                return cvt8(ew2 + (col + ex * 128) * 256 + g * 8);
            }
        };
        half8 b0 = ldE2(0, 0), b1 = ldE2(0, 1);
        #pragma unroll
        for (int kc = 0; kc < 8; ++kc) {
            const half8 c0f = b0, c1f = b1;
            if (kc < 7) { b0 = ldE2(kc + 1, 0); b1 = ldE2(kc + 1, 1); }
            const int koff = kc * 64 + kg16;
            #pragma unroll
            for (int mt = 0; mt < 2; ++mt) {
                const int row = mt * 16 + l15;
                const half8 af = *(const half8*)(smc + H1_B + ((row * 512 + koff) ^ SWZ(row)));
                cA[mt] = MFMA16(af, c0f, cA[mt]);
                cB[mt] = MFMA16(af, c1f, cB[mt]);
            }
        }
        __syncthreads();   // all H1 reads done before H2 overlays H1 low half
        const float b0s = eb2[col], b1s = eb2[128 + col];
        #pragma unroll
        for (int mt = 0; mt < 2; ++mt) {
            #pragma unroll
            for (int j = 0; j < 4; ++j) {
                const int row = mt * 16 + kgrp * 4 + j;
                const float2 cc = *(const float2*)(smc + CF_B + row * 8);
                const float v = fmaxf(cc.x * (cA[mt][j] + b0s) + cc.y * (cB[mt][j] + b1s), 0.f);
                *(_Float16*)(smc + H2_B + ((row * 256 + col * 2) ^ SWZ(row))) = (_Float16)v;
            }
        }
    }
    __syncthreads();

    // ---------- E3: mu = tanh(blend(H2 @ ewm[e]^T + ebm[e]))  M=32 N=17x2 K=128 ----------
    if (wv < 4) {
        const int colt = wv & 1;      // col tile (2x16 covers 17)
        const int mt   = wv >> 1;     // row tile
        f32x4 c0a = {0,0,0,0}, c1a = {0,0,0,0};
        const int col  = colt * 16 + l15;
        const bool vcol = (col < 17);
        const int arow = mt * 16 + l15;
        for (int kc = 0; kc < 4; ++kc) {
            const int koff = kc * 64 + kg16;
            const half8 af = *(const half8*)(smc + H2_B + ((arow * 256 + koff) ^ SWZ(arow)));
            half8 b0, b1;
            if constexpr (USE_WS) {
                b0 = *(const half8*)(wsw + WS_EM + (colt * 4 + kc) * 512 + lB);
                b1 = *(const half8*)(wsw + WS_EM + ((2 + colt) * 4 + kc) * 512 + lB);
            } else {
                const int g = kc * 4 + kgrp;
                b0 = vcol ? cvt8(ewm + col * 128 + g * 8)        : zf;
                b1 = vcol ? cvt8(ewm + (17 + col) * 128 + g * 8) : zf;
            }
            c0a = MFMA16(af, b0, c0a);
            c1a = MFMA16(af, b1, c1a);
        }
        if (vcol) {
            const float b0 = ebm[col], b1 = ebm[17 + col];
            #pragma unroll
            for (int j = 0; j < 4; ++j) {
                const int row = mt * 16 + kgrp * 4 + j;
                const float2 cc = *(const float2*)(smc + CF_B + row * 8);
                const float z = cc.x * (c0a[j] + b0) + cc.y * (c1a[j] + b1);
                const float e2x = __expf(2.f * z);            // tanh(z) = 1 - 2/(e^{2z}+1)
                out[(long)(base + row) * 17 + col] = 1.f - 2.f / (e2x + 1.f);
            }
        }
    }
}

extern "C" void kernel_launch(void* const* d_in, const int* in_sizes, int n_in,
                              void* d_out, int out_size, void* d_ws, size_t ws_size,
                              hipStream_t stream) {
    (void)in_sizes; (void)n_in; (void)out_size;
    const float* states = (const float*)d_in[0];
    const float* bw1 = (const float*)d_in[1];
    const float* bb1 = (const float*)d_in[2];
    const float* bw2 = (const float*)d_in[3];
    const float* bb2 = (const float*)d_in[4];
    const float* bwo = (const float*)d_in[5];
    const float* bbo = (const float*)d_in[6];
    const float* ew1 = (const float*)d_in[7];
    const float* eb1 = (const float*)d_in[8];
    const float* ew2 = (const float*)d_in[9];
    const float* eb2 = (const float*)d_in[10];
    const float* ewm = (const float*)d_in[11];
    const float* ebm = (const float*)d_in[12];
    float* out = (float*)d_out;

    const int nblk = 65536 / MT;   // 2048

    if (d_ws != nullptr && ws_size >= (size_t)WS_BYTES) {
        _Float16* wsw = (_Float16*)d_ws;
        prep_weights<<<dim3((WS_HALFS + 255) / 256), dim3(256), 0, stream>>>(
            bw1, bb1, bw2, ew1, eb1, ew2, ewm, wsw);
        actor_kernel<true><<<dim3(nblk), dim3(T), LDS_BYTES, stream>>>(
            states, bw1, bb1, bw2, bb2, bwo, bbo,
            ew1, eb1, ew2, eb2, ewm, ebm, wsw, out);
    } else {
        actor_kernel<false><<<dim3(nblk), dim3(T), LDS_BYTES, stream>>>(
            states, bw1, bb1, bw2, bb2, bwo, bbo,
            ew1, eb1, ew2, eb2, ewm, ebm, nullptr, out);
    }
}